// Round 4
// baseline (258.180 us; speedup 1.0000x reference)
//
#include <hip/hip_runtime.h>
#include <stdint.h>

typedef unsigned int u32;
typedef unsigned short u16b;

#define NACC   31
#define NSHIFT 15
#define ROWB   4096     // bytes per (c,b) row: 2048 positions * 2 planes
#define NBLK   2048     // 2048 blocks * 4 waves = 8192 waves, 1 row each
#define NSH    32       // shadow copies of each counter
#define TICKET (62 * NSH)

// 16 input bytes = positions 8k..8k+7, byte 2i = plane0, 2i+1 = plane1.
// Returns chunk16 = plane0 bits 0..7 | plane1 bits 0..7 << 8 (bit i = pos 8k+i).
// 0/1-byte->bit: q = b0|b1<<8|b2<<16|b3<<24 (b in {0,1});
// q*0x01020408 puts b0..b3 at bits 24..27 carry-free.
__device__ __forceinline__ u32 chunk16(uint4 v) {
    const u32 q0 = __byte_perm(v.x, v.y, 0x6420);   // plane0 pos +0..3
    const u32 q1 = __byte_perm(v.x, v.y, 0x7531);   // plane1 pos +0..3
    const u32 q2 = __byte_perm(v.z, v.w, 0x6420);   // plane0 pos +4..7
    const u32 q3 = __byte_perm(v.z, v.w, 0x7531);   // plane1 pos +4..7
    const u32 n0 = (q0 * 0x01020408u) >> 24;
    const u32 n1 = (q1 * 0x01020408u) >> 24;
    const u32 n2 = (q2 * 0x01020408u) >> 24;
    const u32 n3 = (q3 * 0x01020408u) >> 24;
    return (n0 | (n2 << 4)) | ((n1 | (n3 << 4)) << 8);
}

// acc reg i holds shifts j=2i (num | den<<8) and j=2i+1 (num<<16 | den<<24).
// Per-row per-lane num,den <= 64 so byte fields never carry.
#define ACCUM(J, X0, X1, K0, K1) do {                                   \
        const u32 nm_ = __popc(X0) + __popc(X1);                        \
        const u32 dn_ = __popc(K0) + __popc(K1);                        \
        if ((J) & 1) acc[(J) >> 1] += (nm_ << 16) | (dn_ << 24);        \
        else         acc[(J) >> 1] += nm_ | (dn_ << 8);                 \
    } while (0)

// One wave per row. Lane l owns positions 32l..32l+31 per plane (u32 word,
// bit j = position 32l+j); ring = the 64-lane wave (64*32 = 2048).
// Loads are fully coalesced (lane l: 16B at chunk l+64t); ownership is
// restored through a 512B/array per-wave LDS transpose (wave-synchronous).
__global__ __launch_bounds__(256, 4) void hd_main(
    const unsigned char* __restrict__ ia, const unsigned char* __restrict__ ma,
    const unsigned char* __restrict__ ib, const unsigned char* __restrict__ mb,
    u32* __restrict__ cnt, float* __restrict__ out)
{
    const int tid  = threadIdx.x;
    const int lane = tid & 63;
    const int wv   = tid >> 6;
    const int row  = blockIdx.x * 4 + wv;     // 0..8191

    __shared__ alignas(16) u32 stg[4][4][128];   // [wave][array][512B]
    __shared__ alignas(16) u32 red[32][132];     // row 31 = dummy
    __shared__ u32 gathered[62];
    __shared__ u32 lastFlag;

    // ---- fully-coalesced global loads (16 x dwordx4, 1KB contiguous each) --
    const uint4* pa = (const uint4*)(ia + (size_t)row * ROWB);
    const uint4* pm = (const uint4*)(ma + (size_t)row * ROWB);
    const uint4* pb = (const uint4*)(ib + (size_t)row * ROWB);
    const uint4* pn = (const uint4*)(mb + (size_t)row * ROWB);

    const uint4 va0 = pa[lane], va1 = pa[lane + 64], va2 = pa[lane + 128], va3 = pa[lane + 192];
    const uint4 vm0 = pm[lane], vm1 = pm[lane + 64], vm2 = pm[lane + 128], vm3 = pm[lane + 192];
    const uint4 vb0 = pb[lane], vb1 = pb[lane + 64], vb2 = pb[lane + 128], vb3 = pb[lane + 192];
    const uint4 vn0 = pn[lane], vn1 = pn[lane + 64], vn2 = pn[lane + 128], vn3 = pn[lane + 192];

    // ---- pack to bits and stage chunk16 at chunk index l+64t ----
    {
        u16b* sA = (u16b*)&stg[wv][0][0];
        u16b* sM = (u16b*)&stg[wv][1][0];
        u16b* sB = (u16b*)&stg[wv][2][0];
        u16b* sN = (u16b*)&stg[wv][3][0];
        sA[lane] = (u16b)chunk16(va0); sA[lane + 64] = (u16b)chunk16(va1);
        sA[lane + 128] = (u16b)chunk16(va2); sA[lane + 192] = (u16b)chunk16(va3);
        sM[lane] = (u16b)chunk16(vm0); sM[lane + 64] = (u16b)chunk16(vm1);
        sM[lane + 128] = (u16b)chunk16(vm2); sM[lane + 192] = (u16b)chunk16(vm3);
        sB[lane] = (u16b)chunk16(vb0); sB[lane + 64] = (u16b)chunk16(vb1);
        sB[lane + 128] = (u16b)chunk16(vb2); sB[lane + 192] = (u16b)chunk16(vb3);
        sN[lane] = (u16b)chunk16(vn0); sN[lane + 64] = (u16b)chunk16(vn1);
        sN[lane + 128] = (u16b)chunk16(vn2); sN[lane + 192] = (u16b)chunk16(vn3);
    }

    // ---- gather own words: chunks 4l..4l+3 (in-wave DS pipe is in-order) --
    u32 A0, A1, M0, M1, B0, B1, N0, N1;
    {
        u32 w0, w1;
        w0 = stg[wv][0][2 * lane]; w1 = stg[wv][0][2 * lane + 1];
        A0 = __byte_perm(w0, w1, 0x6420); A1 = __byte_perm(w0, w1, 0x7531);
        w0 = stg[wv][1][2 * lane]; w1 = stg[wv][1][2 * lane + 1];
        M0 = __byte_perm(w0, w1, 0x6420); M1 = __byte_perm(w0, w1, 0x7531);
        w0 = stg[wv][2][2 * lane]; w1 = stg[wv][2][2 * lane + 1];
        B0 = __byte_perm(w0, w1, 0x6420); B1 = __byte_perm(w0, w1, 0x7531);
        w0 = stg[wv][3][2 * lane]; w1 = stg[wv][3][2 * lane + 1];
        N0 = __byte_perm(w0, w1, 0x6420); N1 = __byte_perm(w0, w1, 0x7531);
    }

    u32 acc[16];
#pragma unroll
    for (int i = 0; i < 16; ++i) acc[i] = 0u;

    const int prevL = (lane + 63) & 63;
    const int nextL = (lane + 1) & 63;
    const u32 pA0 = __shfl(A0, prevL, 64), pA1 = __shfl(A1, prevL, 64);
    const u32 pM0 = __shfl(M0, prevL, 64), pM1 = __shfl(M1, prevL, 64);
    const u32 nA0 = __shfl(A0, nextL, 64), nA1 = __shfl(A1, nextL, 64);
    const u32 nM0 = __shfl(M0, nextL, 64), nM1 = __shfl(M1, nextL, 64);

    {   // s = 0  (j = 15)
        const u32 k0 = M0 & N0, k1 = M1 & N1;
        ACCUM(15, (A0 ^ B0) & k0, (A1 ^ B1) & k1, k0, k1);
    }
#pragma unroll
    for (int s = 1; s <= NSHIFT; ++s) {
        {   // roll right by s: rolled[p] = orig[p-s]   (j = 15+s)
            const u32 ra0 = (A0 << s) | (pA0 >> (32 - s));
            const u32 ra1 = (A1 << s) | (pA1 >> (32 - s));
            const u32 rm0 = (M0 << s) | (pM0 >> (32 - s));
            const u32 rm1 = (M1 << s) | (pM1 >> (32 - s));
            const u32 k0 = rm0 & N0, k1 = rm1 & N1;
            ACCUM(15 + s, (ra0 ^ B0) & k0, (ra1 ^ B1) & k1, k0, k1);
        }
        {   // roll left by s: rolled[p] = orig[p+s]    (j = 15-s)
            const u32 ra0 = (A0 >> s) | (nA0 << (32 - s));
            const u32 ra1 = (A1 >> s) | (nA1 << (32 - s));
            const u32 rm0 = (M0 >> s) | (nM0 << (32 - s));
            const u32 rm1 = (M1 >> s) | (nM1 << (32 - s));
            const u32 k0 = rm0 & N0, k1 = rm1 & N1;
            ACCUM(15 - s, (ra0 ^ B0) & k0, (ra1 ^ B1) & k1, k0, k1);
        }
    }

    // ---- unpack byte-fields to num|den<<16, half-butterfly, store to LDS --
    u32 vals[NACC];
#pragma unroll
    for (int i = 0; i < 16; ++i) {
        const u32 a = acc[i];
        vals[2 * i] = __byte_perm(a, 0u, 0x4140);        // num|den<<16 (even j)
        if (2 * i + 1 < NACC) vals[2 * i + 1] = __byte_perm(a, 0u, 0x4342);
    }
#pragma unroll
    for (int j = 0; j < NACC; ++j) vals[j] += __shfl_xor(vals[j], 32, 64);
    // lanes<32 write row j, lanes>=32 write row j+1 (j=30 -> dummy row 31)
#pragma unroll
    for (int j = 0; j < NACC; j += 2) {
        const u32 v = (j + 1 < NACC && (lane & 32)) ? vals[j + 1] : vals[j];
        red[j + (lane >> 5)][wv * 32 + (lane & 31)] = v;
    }
    __syncthreads();

    // ---- block reduce (8 threads per j) + shadowed global atomics ----
    if (tid < 248) {
        const int j = tid >> 3, c = tid & 7;
        const uint4* p = (const uint4*)&red[j][c * 16];
        u32 s = 0;
#pragma unroll
        for (int i = 0; i < 4; ++i) {
            const uint4 v = p[i];
            s += v.x + v.y + v.z + v.w;        // packed: fields stay < 2^16
        }
        s += __shfl_xor(s, 1, 64);
        s += __shfl_xor(s, 2, 64);
        s += __shfl_xor(s, 4, 64);
        if (c == 0) {
            const int sh = blockIdx.x & (NSH - 1);
            atomicAdd(&cnt[j * NSH + sh], s & 0xFFFFu);          // num_j
            atomicAdd(&cnt[(31 + j) * NSH + sh], s >> 16);       // den_j
        }
    }

    // ---- last-block-done fused finalize ----
    __threadfence();
    __syncthreads();
    if (tid == 0) {
        const u32 t = atomicAdd(&cnt[TICKET], 1u);
        lastFlag = (t == NBLK - 1) ? 1u : 0u;
    }
    __syncthreads();
    if (lastFlag) {
        __threadfence();   // acquire: other blocks' adds precede their tickets
        if (tid < 248) {
            const int j = tid >> 2, q = tid & 3;     // j 0..61, 8 shadows each
            u32 s = 0;
#pragma unroll
            for (int i = 0; i < 8; ++i)
                s += __hip_atomic_load(&cnt[j * NSH + q * 8 + i],
                                       __ATOMIC_RELAXED, __HIP_MEMORY_SCOPE_AGENT);
            s += __shfl_xor(s, 1, 64);
            s += __shfl_xor(s, 2, 64);
            if (q == 0) gathered[j] = s;
        }
        __syncthreads();
        float f = 1.0f;
        if (tid < NACC) f = (float)gathered[tid] / (float)gathered[31 + tid];
        if (tid < 64) {
#pragma unroll
            for (int o = 32; o > 0; o >>= 1) f = fminf(f, __shfl_xor(f, o, 64));
            if (tid == 0) out[0] = fminf(f, 1.0f);
        }
    }
}

extern "C" void kernel_launch(void* const* d_in, const int* in_sizes, int n_in,
                              void* d_out, int out_size, void* d_ws, size_t ws_size,
                              hipStream_t stream)
{
    const unsigned char* ia = (const unsigned char*)d_in[0];  // iris_codes_a
    const unsigned char* ma = (const unsigned char*)d_in[1];  // mask_codes_a
    const unsigned char* ib = (const unsigned char*)d_in[2];  // iris_codes_b
    const unsigned char* mb = (const unsigned char*)d_in[3];  // mask_codes_b
    u32* cnt = (u32*)d_ws;                    // [62][32] shadows + 1 ticket

    hipMemsetAsync(d_ws, 0, (62 * NSH + 1) * sizeof(u32), stream);
    hd_main<<<dim3(NBLK), dim3(256), 0, stream>>>(ia, ma, ib, mb, cnt, (float*)d_out);
}

// Round 5
// 42.606 us; speedup vs baseline: 6.0597x; 6.0597x over previous
//
#include <hip/hip_runtime.h>
#include <stdint.h>

typedef unsigned int u32;
typedef unsigned short u16b;

#define NACC   31
#define NSHIFT 15
#define ROWB   4096     // bytes per (c,b) row: 2048 positions * 2 planes
#define NBLK   2048     // 2048 blocks * 4 waves = 8192 waves, 1 row each
#define NSH    32       // shadow copies of each counter

// 16 input bytes = positions 8k..8k+7, byte 2i = plane0, 2i+1 = plane1.
// Returns chunk16 = plane0 bits 0..7 | plane1 bits 0..7 << 8 (bit i = pos 8k+i).
// 0/1-byte->bit: q = b0|b1<<8|b2<<16|b3<<24 (b in {0,1});
// q*0x01020408 puts b0..b3 at bits 24..27 carry-free.
__device__ __forceinline__ u32 chunk16(uint4 v) {
    const u32 q0 = __byte_perm(v.x, v.y, 0x6420);   // plane0 pos +0..3
    const u32 q1 = __byte_perm(v.x, v.y, 0x7531);   // plane1 pos +0..3
    const u32 q2 = __byte_perm(v.z, v.w, 0x6420);   // plane0 pos +4..7
    const u32 q3 = __byte_perm(v.z, v.w, 0x7531);   // plane1 pos +4..7
    const u32 n0 = (q0 * 0x01020408u) >> 24;
    const u32 n1 = (q1 * 0x01020408u) >> 24;
    const u32 n2 = (q2 * 0x01020408u) >> 24;
    const u32 n3 = (q3 * 0x01020408u) >> 24;
    return (n0 | (n2 << 4)) | ((n1 | (n3 << 4)) << 8);
}

// acc reg i holds shifts j=2i (num | den<<8) and j=2i+1 (num<<16 | den<<24).
// Per-row per-lane num,den <= 64 so byte fields never carry.
#define ACCUM(J, X0, X1, K0, K1) do {                                   \
        const u32 nm_ = __popc(X0) + __popc(X1);                        \
        const u32 dn_ = __popc(K0) + __popc(K1);                        \
        if ((J) & 1) acc[(J) >> 1] += (nm_ << 16) | (dn_ << 24);        \
        else         acc[(J) >> 1] += nm_ | (dn_ << 8);                 \
    } while (0)

// One wave per row. Lane l owns positions 32l..32l+31 per plane (u32 word,
// bit j = position 32l+j); ring = the 64-lane wave (64*32 = 2048).
// Loads are fully coalesced (lane l: 16B at chunk l+64t); ownership is
// restored through a 512B/array per-wave LDS transpose (wave-synchronous).
// NO device-scope fences anywhere (round-4 lesson: a per-block
// __threadfence on CDNA4 = L2 writeback/invalidate storm, 10x slowdown).
__global__ __launch_bounds__(256, 4) void hd_main(
    const unsigned char* __restrict__ ia, const unsigned char* __restrict__ ma,
    const unsigned char* __restrict__ ib, const unsigned char* __restrict__ mb,
    u32* __restrict__ cnt)
{
    const int tid  = threadIdx.x;
    const int lane = tid & 63;
    const int wv   = tid >> 6;
    const int row  = blockIdx.x * 4 + wv;     // 0..8191

    __shared__ alignas(16) u32 stg[4][4][128];   // [wave][array][512B]
    __shared__ alignas(16) u32 red[32][132];     // row 31 = dummy

    // ---- fully-coalesced global loads (16 x dwordx4, 1KB contiguous each) --
    const uint4* pa = (const uint4*)(ia + (size_t)row * ROWB);
    const uint4* pm = (const uint4*)(ma + (size_t)row * ROWB);
    const uint4* pb = (const uint4*)(ib + (size_t)row * ROWB);
    const uint4* pn = (const uint4*)(mb + (size_t)row * ROWB);

    const uint4 va0 = pa[lane], va1 = pa[lane + 64], va2 = pa[lane + 128], va3 = pa[lane + 192];
    const uint4 vm0 = pm[lane], vm1 = pm[lane + 64], vm2 = pm[lane + 128], vm3 = pm[lane + 192];
    const uint4 vb0 = pb[lane], vb1 = pb[lane + 64], vb2 = pb[lane + 128], vb3 = pb[lane + 192];
    const uint4 vn0 = pn[lane], vn1 = pn[lane + 64], vn2 = pn[lane + 128], vn3 = pn[lane + 192];

    // ---- pack to bits and stage chunk16 at chunk index l+64t ----
    {
        u16b* sA = (u16b*)&stg[wv][0][0];
        u16b* sM = (u16b*)&stg[wv][1][0];
        u16b* sB = (u16b*)&stg[wv][2][0];
        u16b* sN = (u16b*)&stg[wv][3][0];
        sA[lane] = (u16b)chunk16(va0); sA[lane + 64] = (u16b)chunk16(va1);
        sA[lane + 128] = (u16b)chunk16(va2); sA[lane + 192] = (u16b)chunk16(va3);
        sM[lane] = (u16b)chunk16(vm0); sM[lane + 64] = (u16b)chunk16(vm1);
        sM[lane + 128] = (u16b)chunk16(vm2); sM[lane + 192] = (u16b)chunk16(vm3);
        sB[lane] = (u16b)chunk16(vb0); sB[lane + 64] = (u16b)chunk16(vb1);
        sB[lane + 128] = (u16b)chunk16(vb2); sB[lane + 192] = (u16b)chunk16(vb3);
        sN[lane] = (u16b)chunk16(vn0); sN[lane + 64] = (u16b)chunk16(vn1);
        sN[lane + 128] = (u16b)chunk16(vn2); sN[lane + 192] = (u16b)chunk16(vn3);
    }

    // ---- gather own words: chunks 4l..4l+3 (in-wave DS pipe is in-order) --
    u32 A0, A1, M0, M1, B0, B1, N0, N1;
    {
        u32 w0, w1;
        w0 = stg[wv][0][2 * lane]; w1 = stg[wv][0][2 * lane + 1];
        A0 = __byte_perm(w0, w1, 0x6420); A1 = __byte_perm(w0, w1, 0x7531);
        w0 = stg[wv][1][2 * lane]; w1 = stg[wv][1][2 * lane + 1];
        M0 = __byte_perm(w0, w1, 0x6420); M1 = __byte_perm(w0, w1, 0x7531);
        w0 = stg[wv][2][2 * lane]; w1 = stg[wv][2][2 * lane + 1];
        B0 = __byte_perm(w0, w1, 0x6420); B1 = __byte_perm(w0, w1, 0x7531);
        w0 = stg[wv][3][2 * lane]; w1 = stg[wv][3][2 * lane + 1];
        N0 = __byte_perm(w0, w1, 0x6420); N1 = __byte_perm(w0, w1, 0x7531);
    }

    u32 acc[16];
#pragma unroll
    for (int i = 0; i < 16; ++i) acc[i] = 0u;

    const int prevL = (lane + 63) & 63;
    const int nextL = (lane + 1) & 63;
    const u32 pA0 = __shfl(A0, prevL, 64), pA1 = __shfl(A1, prevL, 64);
    const u32 pM0 = __shfl(M0, prevL, 64), pM1 = __shfl(M1, prevL, 64);
    const u32 nA0 = __shfl(A0, nextL, 64), nA1 = __shfl(A1, nextL, 64);
    const u32 nM0 = __shfl(M0, nextL, 64), nM1 = __shfl(M1, nextL, 64);

    {   // s = 0  (j = 15)
        const u32 k0 = M0 & N0, k1 = M1 & N1;
        ACCUM(15, (A0 ^ B0) & k0, (A1 ^ B1) & k1, k0, k1);
    }
#pragma unroll
    for (int s = 1; s <= NSHIFT; ++s) {
        {   // roll right by s: rolled[p] = orig[p-s]   (j = 15+s)
            const u32 ra0 = (A0 << s) | (pA0 >> (32 - s));
            const u32 ra1 = (A1 << s) | (pA1 >> (32 - s));
            const u32 rm0 = (M0 << s) | (pM0 >> (32 - s));
            const u32 rm1 = (M1 << s) | (pM1 >> (32 - s));
            const u32 k0 = rm0 & N0, k1 = rm1 & N1;
            ACCUM(15 + s, (ra0 ^ B0) & k0, (ra1 ^ B1) & k1, k0, k1);
        }
        {   // roll left by s: rolled[p] = orig[p+s]    (j = 15-s)
            const u32 ra0 = (A0 >> s) | (nA0 << (32 - s));
            const u32 ra1 = (A1 >> s) | (nA1 << (32 - s));
            const u32 rm0 = (M0 >> s) | (nM0 << (32 - s));
            const u32 rm1 = (M1 >> s) | (nM1 << (32 - s));
            const u32 k0 = rm0 & N0, k1 = rm1 & N1;
            ACCUM(15 - s, (ra0 ^ B0) & k0, (ra1 ^ B1) & k1, k0, k1);
        }
    }

    // ---- unpack byte-fields to num|den<<16, half-butterfly, store to LDS --
    u32 vals[NACC];
#pragma unroll
    for (int i = 0; i < 16; ++i) {
        const u32 a = acc[i];
        vals[2 * i] = __byte_perm(a, 0u, 0x4140);        // num|den<<16 (even j)
        if (2 * i + 1 < NACC) vals[2 * i + 1] = __byte_perm(a, 0u, 0x4342);
    }
#pragma unroll
    for (int j = 0; j < NACC; ++j) vals[j] += __shfl_xor(vals[j], 32, 64);
    // lanes<32 write row j, lanes>=32 write row j+1 (j=30 -> dummy row 31)
#pragma unroll
    for (int j = 0; j < NACC; j += 2) {
        const u32 v = (j + 1 < NACC && (lane & 32)) ? vals[j + 1] : vals[j];
        red[j + (lane >> 5)][wv * 32 + (lane & 31)] = v;
    }
    __syncthreads();

    // ---- block reduce (8 threads per j) + shadowed global atomics ----
    if (tid < 248) {
        const int j = tid >> 3, c = tid & 7;
        const uint4* p = (const uint4*)&red[j][c * 16];
        u32 s = 0;
#pragma unroll
        for (int i = 0; i < 4; ++i) {
            const uint4 v = p[i];
            s += v.x + v.y + v.z + v.w;        // packed: fields stay < 2^16
        }
        s += __shfl_xor(s, 1, 64);
        s += __shfl_xor(s, 2, 64);
        s += __shfl_xor(s, 4, 64);
        if (c == 0) {
            const int sh = blockIdx.x & (NSH - 1);
            atomicAdd(&cnt[j * NSH + sh], s & 0xFFFFu);          // num_j
            atomicAdd(&cnt[(31 + j) * NSH + sh], s >> 16);       // den_j
        }
    }
    // no fence: device-scope atomics + kernel-boundary ordering suffice for
    // the separate finalize launch.
}

// One block, 256 threads: fold 32 shadows per counter (vector loads),
// 31 divisions, min, clamp to 1.
__global__ void hd_finalize(const u32* __restrict__ cnt, float* __restrict__ out)
{
    __shared__ u32 gathered[62];
    const int tid = threadIdx.x;
    if (tid < 248) {
        const int j = tid >> 2, q = tid & 3;     // 4 threads per counter
        const uint4* p = (const uint4*)&cnt[j * NSH + q * 8];
        const uint4 v0 = p[0], v1 = p[1];
        u32 s = v0.x + v0.y + v0.z + v0.w + v1.x + v1.y + v1.z + v1.w;
        s += __shfl_xor(s, 1, 64);
        s += __shfl_xor(s, 2, 64);
        if (q == 0) gathered[j] = s;
    }
    __syncthreads();
    if (tid < 64) {
        float f = 1.0f;
        if (tid < NACC) f = (float)gathered[tid] / (float)gathered[31 + tid];
#pragma unroll
        for (int o = 32; o > 0; o >>= 1) f = fminf(f, __shfl_xor(f, o, 64));
        if (tid == 0) out[0] = fminf(f, 1.0f);
    }
}

extern "C" void kernel_launch(void* const* d_in, const int* in_sizes, int n_in,
                              void* d_out, int out_size, void* d_ws, size_t ws_size,
                              hipStream_t stream)
{
    const unsigned char* ia = (const unsigned char*)d_in[0];  // iris_codes_a
    const unsigned char* ma = (const unsigned char*)d_in[1];  // mask_codes_a
    const unsigned char* ib = (const unsigned char*)d_in[2];  // iris_codes_b
    const unsigned char* mb = (const unsigned char*)d_in[3];  // mask_codes_b
    u32* cnt = (u32*)d_ws;                    // [62][32] shadow counters

    hipMemsetAsync(d_ws, 0, 62 * NSH * sizeof(u32), stream);
    hd_main<<<dim3(NBLK), dim3(256), 0, stream>>>(ia, ma, ib, mb, cnt);
    hd_finalize<<<dim3(1), dim3(256), 0, stream>>>(cnt, (float*)d_out);
}

// Round 6
// 40.248 us; speedup vs baseline: 6.4148x; 1.0586x over previous
//
#include <hip/hip_runtime.h>
#include <stdint.h>

typedef unsigned int u32;

#define NACC   31
#define NSHIFT 15
#define ROWB   4096     // bytes per (c,b) row: 2048 positions * 2 planes
#define NBLK   512      // 512 blocks * 4 waves = 2048 waves
#define RPW    4        // rows per wave  (512*4*4 = 8192 rows)
#define NSH    32       // shadow copies of each counter

// 16 input bytes = positions q..q+7, byte 2i = plane0(q+i), 2i+1 = plane1(q+i).
// Appends 8 bits to P0 (plane0) and P1 (plane1) at bit offset 8t.
// 0/1-byte->bit: q = b0|b1<<8|b2<<16|b3<<24 (b in {0,1});
// q*0x01020408 puts b0..b3 at bits 24..27 carry-free.
__device__ __forceinline__ void pack16(uint4 v, u32& P0, u32& P1, int t) {
    const u32 q0 = __byte_perm(v.x, v.y, 0x6420);  // plane0, +0..3
    const u32 q1 = __byte_perm(v.x, v.y, 0x7531);  // plane1, +0..3
    const u32 q2 = __byte_perm(v.z, v.w, 0x6420);  // plane0, +4..7
    const u32 q3 = __byte_perm(v.z, v.w, 0x7531);  // plane1, +4..7
    const u32 n0 = (q0 * 0x01020408u) >> 24;
    const u32 n1 = (q1 * 0x01020408u) >> 24;
    const u32 n2 = (q2 * 0x01020408u) >> 24;
    const u32 n3 = (q3 * 0x01020408u) >> 24;
    P0 |= (n0 | (n2 << 4)) << (8 * t);
    P1 |= (n1 | (n3 << 4)) << (8 * t);
}

// One wave per 4 consecutive rows, software-pipelined: while the 31-shift
// popcount block for row r runs (~1100 cyc VALU), row r+1's 16 dwordx4
// loads are in flight. Lane l owns positions 32l..32l+31 per plane (u32,
// bit j = position 32l+j); ring = the 64-lane wave. |s|<=15 < 32 so a
// rotation needs only lane+-1 words (8 shfls/row).
// No device-scope fences (round-4 lesson: per-block __threadfence on CDNA4
// = L2 writeback storm, 10x slowdown).
__global__ __launch_bounds__(256, 2) void hd_main(
    const unsigned char* __restrict__ ia, const unsigned char* __restrict__ ma,
    const unsigned char* __restrict__ ib, const unsigned char* __restrict__ mb,
    u32* __restrict__ cnt)
{
    const int tid  = threadIdx.x;
    const int lane = tid & 63;
    const int wv   = tid >> 6;
    const int gw   = blockIdx.x * 4 + wv;        // 0..2047

    const int prevL = (lane + 63) & 63;
    const int nextL = (lane + 1) & 63;

    u32 acc[NACC];                               // num | den<<16 per shift
#pragma unroll
    for (int j = 0; j < NACC; ++j) acc[j] = 0u;

    // lane-contiguous 64B per array-row: lane l -> uint4s l*4 .. l*4+3
    const uint4* pa = (const uint4*)(ia + (size_t)gw * RPW * ROWB) + lane * 4;
    const uint4* pm = (const uint4*)(ma + (size_t)gw * RPW * ROWB) + lane * 4;
    const uint4* pb = (const uint4*)(ib + (size_t)gw * RPW * ROWB) + lane * 4;
    const uint4* pn = (const uint4*)(mb + (size_t)gw * RPW * ROWB) + lane * 4;
    const int rstep = ROWB / 16;                 // row stride in uint4

    uint4 bA[4], bM[4], bB[4], bN[4];
#pragma unroll
    for (int t = 0; t < 4; ++t) {
        bA[t] = pa[t]; bM[t] = pm[t]; bB[t] = pb[t]; bN[t] = pn[t];
    }

#pragma unroll
    for (int r = 0; r < RPW; ++r) {
        // ---- pack row r (consumes bA..bN, frees them for the prefetch) ----
        u32 A0 = 0, A1 = 0, M0 = 0, M1 = 0, B0 = 0, B1 = 0, N0 = 0, N1 = 0;
#pragma unroll
        for (int t = 0; t < 4; ++t) {
            pack16(bA[t], A0, A1, t);
            pack16(bM[t], M0, M1, t);
            pack16(bB[t], B0, B1, t);
            pack16(bN[t], N0, N1, t);
        }

        // ---- issue row r+1 loads; they complete under the shift block ----
        if (r + 1 < RPW) {
            const int o = (r + 1) * rstep;
#pragma unroll
            for (int t = 0; t < 4; ++t) {
                bA[t] = pa[o + t]; bM[t] = pm[o + t];
                bB[t] = pb[o + t]; bN[t] = pn[o + t];
            }
        }

        // ---- neighbors + 31 rotations (pure VALU, ~1100 cyc) ----
        const u32 pA0 = __shfl(A0, prevL, 64), pA1 = __shfl(A1, prevL, 64);
        const u32 pM0 = __shfl(M0, prevL, 64), pM1 = __shfl(M1, prevL, 64);
        const u32 nA0 = __shfl(A0, nextL, 64), nA1 = __shfl(A1, nextL, 64);
        const u32 nM0 = __shfl(M0, nextL, 64), nM1 = __shfl(M1, nextL, 64);

        {   // s = 0 (j = 15)
            const u32 k0 = M0 & N0, k1 = M1 & N1;
            const u32 nm = __popc((A0 ^ B0) & k0) + __popc((A1 ^ B1) & k1);
            const u32 dn = __popc(k0) + __popc(k1);
            acc[15] += nm | (dn << 16);
        }
#pragma unroll
        for (int s = 1; s <= NSHIFT; ++s) {
            {   // roll right by s: rolled[p] = orig[p-s]  (j = 15+s)
                const u32 ra0 = (A0 << s) | (pA0 >> (32 - s));
                const u32 ra1 = (A1 << s) | (pA1 >> (32 - s));
                const u32 rm0 = (M0 << s) | (pM0 >> (32 - s));
                const u32 rm1 = (M1 << s) | (pM1 >> (32 - s));
                const u32 k0 = rm0 & N0, k1 = rm1 & N1;
                const u32 nm = __popc((ra0 ^ B0) & k0) + __popc((ra1 ^ B1) & k1);
                const u32 dn = __popc(k0) + __popc(k1);
                acc[15 + s] += nm | (dn << 16);
            }
            {   // roll left by s: rolled[p] = orig[p+s]   (j = 15-s)
                const u32 ra0 = (A0 >> s) | (nA0 << (32 - s));
                const u32 ra1 = (A1 >> s) | (nA1 << (32 - s));
                const u32 rm0 = (M0 >> s) | (nM0 << (32 - s));
                const u32 rm1 = (M1 >> s) | (nM1 << (32 - s));
                const u32 k0 = rm0 & N0, k1 = rm1 & N1;
                const u32 nm = __popc((ra0 ^ B0) & k0) + __popc((ra1 ^ B1) & k1);
                const u32 dn = __popc(k0) + __popc(k1);
                acc[15 - s] += nm | (dn << 16);
            }
        }
    }

    // ---- per-wave half-butterfly, block reduce in LDS, shadowed atomics ----
    // per-lane fields <= 4*64 = 256; after the 32-xor <= 512; unpacked before
    // block-level summation (block totals up to 16*4096 = 65536 would wrap).
    __shared__ alignas(16) u32 red[32][132];     // row 31 = dummy
#pragma unroll
    for (int j = 0; j < NACC; ++j) acc[j] += __shfl_xor(acc[j], 32, 64);
#pragma unroll
    for (int j = 0; j < NACC; j += 2) {
        const u32 v = (j + 1 < NACC && (lane & 32)) ? acc[j + 1] : acc[j];
        red[j + (lane >> 5)][wv * 32 + (lane & 31)] = v;
    }
    __syncthreads();

    if (tid < 248) {
        const int j = tid >> 3, c = tid & 7;     // 8 threads per counter j
        const uint4* p = (const uint4*)&red[j][c * 16];
        u32 sn = 0, sd = 0;
#pragma unroll
        for (int i = 0; i < 4; ++i) {
            const uint4 v = p[i];
            sn += (v.x & 0xFFFFu) + (v.y & 0xFFFFu) + (v.z & 0xFFFFu) + (v.w & 0xFFFFu);
            sd += (v.x >> 16) + (v.y >> 16) + (v.z >> 16) + (v.w >> 16);
        }
        sn += __shfl_xor(sn, 1, 64); sd += __shfl_xor(sd, 1, 64);
        sn += __shfl_xor(sn, 2, 64); sd += __shfl_xor(sd, 2, 64);
        sn += __shfl_xor(sn, 4, 64); sd += __shfl_xor(sd, 4, 64);
        if (c == 0) {
            const int sh = blockIdx.x & (NSH - 1);
            atomicAdd(&cnt[j * NSH + sh], sn);          // num_j
            atomicAdd(&cnt[(31 + j) * NSH + sh], sd);   // den_j
        }
    }
    // no fence: device-scope atomics + kernel boundary order the finalize.
}

// One block, 256 threads: fold 32 shadows per counter (vector loads),
// 31 divisions, min, clamp to 1.
__global__ void hd_finalize(const u32* __restrict__ cnt, float* __restrict__ out)
{
    __shared__ u32 gathered[62];
    const int tid = threadIdx.x;
    if (tid < 248) {
        const int j = tid >> 2, q = tid & 3;     // 4 threads per counter
        const uint4* p = (const uint4*)&cnt[j * NSH + q * 8];
        const uint4 v0 = p[0], v1 = p[1];
        u32 s = v0.x + v0.y + v0.z + v0.w + v1.x + v1.y + v1.z + v1.w;
        s += __shfl_xor(s, 1, 64);
        s += __shfl_xor(s, 2, 64);
        if (q == 0) gathered[j] = s;
    }
    __syncthreads();
    if (tid < 64) {
        float f = 1.0f;
        if (tid < NACC) f = (float)gathered[tid] / (float)gathered[31 + tid];
#pragma unroll
        for (int o = 32; o > 0; o >>= 1) f = fminf(f, __shfl_xor(f, o, 64));
        if (tid == 0) out[0] = fminf(f, 1.0f);
    }
}

extern "C" void kernel_launch(void* const* d_in, const int* in_sizes, int n_in,
                              void* d_out, int out_size, void* d_ws, size_t ws_size,
                              hipStream_t stream)
{
    const unsigned char* ia = (const unsigned char*)d_in[0];  // iris_codes_a
    const unsigned char* ma = (const unsigned char*)d_in[1];  // mask_codes_a
    const unsigned char* ib = (const unsigned char*)d_in[2];  // iris_codes_b
    const unsigned char* mb = (const unsigned char*)d_in[3];  // mask_codes_b
    u32* cnt = (u32*)d_ws;                    // [62][32] shadow counters

    hipMemsetAsync(d_ws, 0, 62 * NSH * sizeof(u32), stream);
    hd_main<<<dim3(NBLK), dim3(256), 0, stream>>>(ia, ma, ib, mb, cnt);
    hd_finalize<<<dim3(1), dim3(256), 0, stream>>>(cnt, (float*)d_out);
}